// Round 2
// baseline (89.587 us; speedup 1.0000x reference)
//
#include <hip/hip_runtime.h>
#include <math.h>

#define B_ 16
#define N_ 1024
#define K_ 64
#define C_ 128
#define INV_T 14.285714285714286f  // 1/0.07
#define NBLK_MAIN 2048             // 8 q-rows per block (4 waves x 2 rows)

using f32x2 = __attribute__((ext_vector_type(2))) float;

__device__ __forceinline__ float waveReduceSum(float v) {
#pragma unroll
    for (int off = 32; off > 0; off >>= 1)
        v += __shfl_xor(v, off, 64);
    return v;
}

// Kernel 1: L2-normalize k rows -> fp8 e4m3 kn (2 MB, HW cvt).
// Wave per row, 4 rows/wave.
__global__ __launch_bounds__(256) void normalize_k_kernel(
    const float* __restrict__ k, unsigned char* __restrict__ kn) {
    const int lane = threadIdx.x & 63;
    const int wid  = threadIdx.x >> 6;
    const int base = blockIdx.x * 16 + wid * 4;
#pragma unroll
    for (int r = 0; r < 4; ++r) {
        const int row = base + r;                     // 0..16383
        const float2 v = *(const float2*)(k + (size_t)row * C_ + 2 * lane);
        const float ss = waveReduceSum(v.x * v.x + v.y * v.y);
        const float inv = 1.0f / fmaxf(sqrtf(ss), 1e-12f);
        const int pk = __builtin_amdgcn_cvt_pk_fp8_f32(v.x * inv, v.y * inv, 0, false);
        *(unsigned short*)(kn + (size_t)row * C_ + 2 * lane) =
            (unsigned short)(pk & 0xffff);
    }
}

// Kernel 2: one wave per 2 q-rows. q is read as raw fp32 and normalized
// on the fly (each 8-lane group holds the full 128-elem row: 16 elems/lane,
// 3-level xor reduce for ||q||). fp8 k gather: one k-row = one 128B line;
// 8 lanes cover it with a single uint4 load. 9 passes: 0-7 = 64 negatives
// (one row per 8-lane group), pass 8 = positive (all lanes, 1 line).
// Dot accumulates in f32x2 (v_pk_fma_f32); fp8 decode via HW cvt_pk_f32_fp8.
// LSE reductions use only the 3 cross-group xor levels {8,16,32} since sims
// are duplicated across each group's 8 lanes.
__global__ __launch_bounds__(256, 4) void infonce_kernel(
    const float* __restrict__ q, const unsigned char* __restrict__ kn,
    const int* __restrict__ pos_idx, const int* __restrict__ neg_idx,
    float* __restrict__ partials) {
    __shared__ float wave_tot[4], wave_cnt[4];

    const int lane = threadIdx.x & 63;
    const int wid  = threadIdx.x >> 6;
    const int g    = lane >> 3;   // group 0..7
    const int s    = lane & 7;    // sub-lane within group

    const int batch = blockIdx.x & 15;   // XCD-affine batch mapping
    const int chunk = blockIdx.x >> 4;
    const int rbase = chunk * 8 + wid * 2;

    const unsigned char* kb = kn + (size_t)batch * (N_ * C_);

    float tot = 0.0f, cnt = 0.0f;

#pragma unroll
    for (int r = 0; r < 2; ++r) {
        const int n   = rbase + r;
        const int row = batch * N_ + n;

        // This lane's 16 fp32 q elements [s*16 .. s*16+15].
        const float* qrow = q + (size_t)row * C_ + s * 16;
        const float4 f0 = *(const float4*)(qrow + 0);
        const float4 f1 = *(const float4*)(qrow + 4);
        const float4 f2 = *(const float4*)(qrow + 8);
        const float4 f3 = *(const float4*)(qrow + 12);

        // ||q||^2: per-lane partial, then 3 xor levels within the 8-lane
        // group (group covers the whole row exactly once).
        float ss = f0.x * f0.x + f0.y * f0.y + f0.z * f0.z + f0.w * f0.w;
        ss      += f1.x * f1.x + f1.y * f1.y + f1.z * f1.z + f1.w * f1.w;
        ss      += f2.x * f2.x + f2.y * f2.y + f2.z * f2.z + f2.w * f2.w;
        ss      += f3.x * f3.x + f3.y * f3.y + f3.z * f3.z + f3.w * f3.w;
        ss += __shfl_xor(ss, 1, 64);
        ss += __shfl_xor(ss, 2, 64);
        ss += __shfl_xor(ss, 4, 64);
        const float sc = (1.0f / fmaxf(sqrtf(ss), 1e-12f)) * INV_T;

        f32x2 qf[8];
        qf[0] = f32x2{f0.x, f0.y} * sc;
        qf[1] = f32x2{f0.z, f0.w} * sc;
        qf[2] = f32x2{f1.x, f1.y} * sc;
        qf[3] = f32x2{f1.z, f1.w} * sc;
        qf[4] = f32x2{f2.x, f2.y} * sc;
        qf[5] = f32x2{f2.z, f2.w} * sc;
        qf[6] = f32x2{f3.x, f3.y} * sc;
        qf[7] = f32x2{f3.z, f3.w} * sc;

        const int  pidx = pos_idx[row];     // wave-uniform
        const bool pval = pidx >= 0;
        const int  p0   = pval ? pidx : 0;

        // Group g's 8 negative indices, loaded directly (256B row, L1-hot).
        const int* nrow = neg_idx + (size_t)row * K_;
        int nidx[8];
#pragma unroll
        for (int p = 0; p < 8; ++p) nidx[p] = nrow[p * 8 + g];

        float d[9];
#pragma unroll
        for (int p = 0; p < 9; ++p) {
            const unsigned char* kr =
                (p < 8) ? kb + (size_t)(nidx[p] >= 0 ? nidx[p] : 0) * C_
                        : kb + (size_t)p0 * C_;
            const uint4 ku = *(const uint4*)(kr + s * 16);  // 16 fp8 elems
            const unsigned w[4] = {ku.x, ku.y, ku.z, ku.w};
            f32x2 acc = f32x2{0.0f, 0.0f};
#pragma unroll
            for (int i = 0; i < 4; ++i) {
                const f32x2 lo = __builtin_amdgcn_cvt_pk_f32_fp8(w[i], false);
                const f32x2 hi = __builtin_amdgcn_cvt_pk_f32_fp8(w[i], true);
                acc = lo * qf[i * 2 + 0] + acc;   // contracts to v_pk_fma_f32
                acc = hi * qf[i * 2 + 1] + acc;
            }
            float dot = acc[0] + acc[1];
            dot += __shfl_xor(dot, 1, 64);   // intra-group: DPP-fast
            dot += __shfl_xor(dot, 2, 64);
            dot += __shfl_xor(dot, 4, 64);
            d[p] = dot;                       // == logit (q scaled by 1/T)
        }

        const float pos_sim = d[8];           // wave-uniform

        float simv[8];
#pragma unroll
        for (int p = 0; p < 8; ++p)
            simv[p] = (nidx[p] >= 0) ? d[p] : -INFINITY;

        // Max: per-lane over its group's 8 sims, then 3 cross-group levels.
        float m = pos_sim;
#pragma unroll
        for (int p = 0; p < 8; ++p) m = fmaxf(m, simv[p]);
        m = fmaxf(m, __shfl_xor(m, 8, 64));
        m = fmaxf(m, __shfl_xor(m, 16, 64));
        m = fmaxf(m, __shfl_xor(m, 32, 64));

        // Sum: every lane sums its group's 8 exps (identical within group),
        // then 3 cross-group levels sum exactly one copy per group.
        float ssum = 0.0f;
#pragma unroll
        for (int p = 0; p < 8; ++p) ssum += __expf(simv[p] - m);
        ssum += __shfl_xor(ssum, 8, 64);
        ssum += __shfl_xor(ssum, 16, 64);
        ssum += __shfl_xor(ssum, 32, 64);
        ssum += __expf(pos_sim - m);

        const float per_patch = m + __logf(ssum) - pos_sim;
        if (pval) { tot += per_patch; cnt += 1.0f; }
    }

    if (lane == 0) { wave_tot[wid] = tot; wave_cnt[wid] = cnt; }
    __syncthreads();
    if (threadIdx.x == 0) {
        partials[2 * blockIdx.x]     = wave_tot[0] + wave_tot[1] + wave_tot[2] + wave_tot[3];
        partials[2 * blockIdx.x + 1] = wave_cnt[0] + wave_cnt[1] + wave_cnt[2] + wave_cnt[3];
    }
}

// Kernel 3: reduce block partials, emit total / count.
__global__ __launch_bounds__(256) void finalize_kernel(const float* __restrict__ partials,
                                                       float* __restrict__ out, int nblocks) {
    __shared__ float st[256], sc[256];
    float t = 0.0f, c = 0.0f;
    for (int i = threadIdx.x; i < nblocks; i += 256) {
        t += partials[2 * i];
        c += partials[2 * i + 1];
    }
    st[threadIdx.x] = t;
    sc[threadIdx.x] = c;
    __syncthreads();
    for (int off = 128; off > 0; off >>= 1) {
        if (threadIdx.x < off) {
            st[threadIdx.x] += st[threadIdx.x + off];
            sc[threadIdx.x] += sc[threadIdx.x + off];
        }
        __syncthreads();
    }
    if (threadIdx.x == 0) {
        const float cntv = sc[0];
        out[0] = (cntv > 0.0f) ? st[0] / fmaxf(cntv, 1.0f) : 0.0f;
    }
}

extern "C" void kernel_launch(void* const* d_in, const int* in_sizes, int n_in,
                              void* d_out, int out_size, void* d_ws, size_t ws_size,
                              hipStream_t stream) {
    const float* q   = (const float*)d_in[0];
    const float* k   = (const float*)d_in[1];
    const int*   pos = (const int*)d_in[2];
    const int*   neg = (const int*)d_in[3];
    float* out = (float*)d_out;

    float* wsf = (float*)d_ws;
    float* partials = wsf;                                   // 4096 floats
    unsigned char* kn = (unsigned char*)(wsf + 8192);        // 2 MB (fp8)

    normalize_k_kernel<<<1024, 256, 0, stream>>>(k, kn);
    infonce_kernel<<<NBLK_MAIN, 256, 0, stream>>>(q, kn, pos, neg, partials);
    finalize_kernel<<<1, 256, 0, stream>>>(partials, out, NBLK_MAIN);
}